// Round 1
// baseline (472.144 us; speedup 1.0000x reference)
//
#include <hip/hip_runtime.h>
#include <hip/hip_bf16.h>
#include <stdint.h>

#define N_NODES_C 1000000
#define N_GRAPHS_C 4096

typedef __attribute__((ext_vector_type(8))) __bf16 bf16x8;
typedef __attribute__((ext_vector_type(4))) float f32x4;

__device__ __forceinline__ unsigned short f2bf(float f) {
    union { float f; unsigned int u; } v; v.f = f;
    unsigned int r = v.u + 0x7FFFu + ((v.u >> 16) & 1u);   // RNE
    return (unsigned short)(r >> 16);
}
__device__ __forceinline__ unsigned int pack2(float a, float b) {
    return (unsigned int)f2bf(a) | ((unsigned int)f2bf(b) << 16);
}

// Stage 0: per-graph bias c[b][j] = bn[j] + (global_attr[b]@Wg + bg) @ Wn_bot[:,j]
// Also: Wn_top^T -> bf16 (BT[n][k] = Wn[k][n]), and zero the softmax denominators.
__global__ void stage0_kernel(const float* __restrict__ ga, const float* __restrict__ Wg,
                              const float* __restrict__ bg, const float* __restrict__ Wn,
                              const float* __restrict__ bn,
                              float* __restrict__ c, unsigned short* __restrict__ BT,
                              float* __restrict__ denom) {
    int b = blockIdx.x, j = threadIdx.x;   // 4096 blocks x 64 threads
    __shared__ float g[64];
    float acc = bg[j];
#pragma unroll
    for (int m = 0; m < 3; ++m) acc += ga[b * 3 + m] * Wg[m * 64 + j];
    g[j] = acc;
    __syncthreads();
    float cj = bn[j];
#pragma unroll 16
    for (int k = 0; k < 64; ++k) cj += g[k] * Wn[(64 + k) * 64 + j];   // LDS broadcast reads
    c[b * 64 + j] = cj;
    if (b < 64) BT[b * 64 + j] = f2bf(Wn[j * 64 + b]);                 // block b = n, thread j = k
    if (j == 0) denom[b] = 0.0f;
}

// Main: per 256-node block, bf16 MFMA x@Wn_top, fused softplus + Wa-dot + exp,
// write e[node], atomicAdd per-graph denom.
__global__ __launch_bounds__(256) void node_kernel(
    const float* __restrict__ x, const int* __restrict__ nb,
    const float* __restrict__ c, const unsigned short* __restrict__ BTg,
    const float* __restrict__ Wa, const float* __restrict__ ba,
    float* __restrict__ e, float* __restrict__ denom)
{
    // LDS rows padded to 72 bf16 (144 B = 36 dwords): MFMA b128 frag reads are <=2-way banked (free)
    __shared__ __align__(16) unsigned short Alds[256 * 72];
    __shared__ __align__(16) unsigned short Blds[64 * 72];
    __shared__ int seg[256];

    int t = threadIdx.x;
    long base = (long)blockIdx.x * 256;
    bool is64 = nb[N_NODES_C - 1] < 1024;  // int64 layout -> this is a high word (0); int32 -> 4095

    // Stage B (Wn_top^T bf16, 2048 dwords)
    const unsigned int* BTu = (const unsigned int*)BTg;
    unsigned int* BldsU = (unsigned int*)Blds;
#pragma unroll
    for (int i = 0; i < 8; ++i) {
        int flat = t + i * 256;
        BldsU[(flat >> 5) * 36 + (flat & 31)] = BTu[flat];
    }
    // Stage A: coalesced float4 reads of x, convert to bf16 into padded rows
    unsigned int* AldsU = (unsigned int*)Alds;
#pragma unroll
    for (int kq = 0; kq < 16; ++kq) {
        int rel = t + kq * 256;            // float4 index within block tile
        int row = rel >> 4, c4 = rel & 15;
        long node = base + row;
        float4 v = make_float4(0.f, 0.f, 0.f, 0.f);
        if (node < N_NODES_C) v = ((const float4*)x)[base * 16 + rel];
        AldsU[row * 36 + c4 * 2 + 0] = pack2(v.x, v.y);
        AldsU[row * 36 + c4 * 2 + 1] = pack2(v.z, v.w);
    }
    {
        long node = base + t;
        int sv = 0;
        if (node < N_NODES_C) sv = is64 ? nb[2 * node] : nb[node];
        seg[t] = sv;
    }
    __syncthreads();

    int wave = t >> 6, lane = t & 63;
    int quad = lane >> 4, l15 = lane & 15;

    float wa[4];
    float bav = ba[0];
#pragma unroll
    for (int nt = 0; nt < 4; ++nt) wa[nt] = Wa[nt * 16 + l15];

    // Hoist B fragments: B[k][n], lane holds n = l15, k = quad*8 + j (+32 for kh=1)
    bf16x8 bfrag[4][2];
#pragma unroll
    for (int nt = 0; nt < 4; ++nt)
#pragma unroll
        for (int kh = 0; kh < 2; ++kh)
            bfrag[nt][kh] = *(const bf16x8*)&Blds[(nt * 16 + l15) * 72 + quad * 8 + kh * 32];

    for (int t4 = 0; t4 < 4; ++t4) {
        int mrow = wave * 64 + t4 * 16;    // block-relative row of this 16-node tile
        const bf16x8 a0 = *(const bf16x8*)&Alds[(mrow + l15) * 72 + quad * 8];
        const bf16x8 a1 = *(const bf16x8*)&Alds[(mrow + l15) * 72 + quad * 8 + 32];
        f32x4 acc[4];
#pragma unroll
        for (int nt = 0; nt < 4; ++nt) {
            acc[nt] = (f32x4){0.f, 0.f, 0.f, 0.f};
            acc[nt] = __builtin_amdgcn_mfma_f32_16x16x32_bf16(a0, bfrag[nt][0], acc[nt], 0, 0, 0);
            acc[nt] = __builtin_amdgcn_mfma_f32_16x16x32_bf16(a1, bfrag[nt][1], acc[nt], 0, 0, 0);
        }
        // Epilogue. C/D: col = l15 (+16*nt), rows = mrow + quad*4 + reg
        int r0 = mrow + quad * 4;
        int sg0 = seg[r0], sg1 = seg[r0 + 1], sg2 = seg[r0 + 2], sg3 = seg[r0 + 3];
        bool uni = (sg0 == sg3);           // sorted -> equality of ends implies all equal
        float sp0 = 0.f, sp1 = 0.f, sp2 = 0.f, sp3 = 0.f;
#pragma unroll
        for (int nt = 0; nt < 4; ++nt) {
            int col = nt * 16 + l15;
            float c0, c1, c2, c3;
            if (uni) { c0 = c[sg0 * 64 + col]; c1 = c0; c2 = c0; c3 = c0; }
            else {
                c0 = c[sg0 * 64 + col]; c1 = c[sg1 * 64 + col];
                c2 = c[sg2 * 64 + col]; c3 = c[sg3 * 64 + col];
            }
            float y0 = acc[nt].x + c0, y1 = acc[nt].y + c1;
            float y2 = acc[nt].z + c2, y3 = acc[nt].w + c3;
            sp0 += __logf(1.f + __expf(y0)) * wa[nt];
            sp1 += __logf(1.f + __expf(y1)) * wa[nt];
            sp2 += __logf(1.f + __expf(y2)) * wa[nt];
            sp3 += __logf(1.f + __expf(y3)) * wa[nt];
        }
        // Reduce across the 16 lanes of the quad (xor 1,2,4,8 stays inside the quad)
#pragma unroll
        for (int off = 1; off < 16; off <<= 1) {
            sp0 += __shfl_xor(sp0, off, 64);
            sp1 += __shfl_xor(sp1, off, 64);
            sp2 += __shfl_xor(sp2, off, 64);
            sp3 += __shfl_xor(sp3, off, 64);
        }
        float e0 = __expf(sp0 + bav), e1 = __expf(sp1 + bav);
        float e2 = __expf(sp2 + bav), e3 = __expf(sp3 + bav);
        if (l15 == 0) {
            long node0 = base + r0;
            if (node0 + 3 < N_NODES_C) {
                *(float4*)&e[node0] = make_float4(e0, e1, e2, e3);
                float s = e0; int cur = sg0;
                if (sg1 == cur) s += e1; else { atomicAdd(&denom[cur], s); cur = sg1; s = e1; }
                if (sg2 == cur) s += e2; else { atomicAdd(&denom[cur], s); cur = sg2; s = e2; }
                if (sg3 == cur) s += e3; else { atomicAdd(&denom[cur], s); cur = sg3; s = e3; }
                atomicAdd(&denom[cur], s);
            } else {
                float ev[4] = {e0, e1, e2, e3};
                int sg[4] = {sg0, sg1, sg2, sg3};
                for (int i = 0; i < 4; ++i) {
                    if (node0 + i < N_NODES_C) {
                        e[node0 + i] = ev[i];
                        atomicAdd(&denom[sg[i]], ev[i]);
                    }
                }
            }
        }
    }
}

// Finalize: w = e / denom[seg]
__global__ __launch_bounds__(256) void fin_kernel(
    const float* __restrict__ e, const int* __restrict__ nb,
    const float* __restrict__ denom, float* __restrict__ out)
{
    long node0 = (long)(blockIdx.x * 256 + threadIdx.x) * 4;
    if (node0 >= N_NODES_C) return;
    bool is64 = nb[N_NODES_C - 1] < 1024;
    float4 ev = *(const float4*)&e[node0];
    int s0, s1, s2, s3;
    if (is64) {
        int4 a = *(const int4*)&nb[2 * node0];
        int4 b = *(const int4*)&nb[2 * node0 + 4];
        s0 = a.x; s1 = a.z; s2 = b.x; s3 = b.z;
    } else {
        int4 a = *(const int4*)&nb[node0];
        s0 = a.x; s1 = a.y; s2 = a.z; s3 = a.w;
    }
    float4 w;
    w.x = ev.x / denom[s0];
    w.y = ev.y / denom[s1];
    w.z = ev.z / denom[s2];
    w.w = ev.w / denom[s3];
    *(float4*)&out[node0] = w;
}

extern "C" void kernel_launch(void* const* d_in, const int* in_sizes, int n_in,
                              void* d_out, int out_size, void* d_ws, size_t ws_size,
                              hipStream_t stream) {
    const float* x  = (const float*)d_in[0];
    const int*   nb = (const int*)d_in[1];
    const float* ga = (const float*)d_in[2];
    const float* Wg = (const float*)d_in[3];
    const float* bg = (const float*)d_in[4];
    const float* Wn = (const float*)d_in[5];
    const float* bn = (const float*)d_in[6];
    const float* Wa = (const float*)d_in[7];
    const float* ba = (const float*)d_in[8];

    char* ws = (char*)d_ws;
    float* e            = (float*)(ws);                              // 4,000,000 B
    float* c            = (float*)(ws + 4194304);                    // 1 MB
    unsigned short* BT  = (unsigned short*)(ws + 4194304 + 1048576); // 8 KB
    float* denom        = (float*)(ws + 4194304 + 1048576 + 8192);   // 16 KB

    hipLaunchKernelGGL(stage0_kernel, dim3(N_GRAPHS_C), dim3(64), 0, stream,
                       ga, Wg, bg, Wn, bn, c, BT, denom);
    hipLaunchKernelGGL(node_kernel, dim3((N_NODES_C + 255) / 256), dim3(256), 0, stream,
                       x, nb, c, BT, Wa, ba, e, denom);
    hipLaunchKernelGGL(fin_kernel, dim3((N_NODES_C / 4 + 255) / 256), dim3(256), 0, stream,
                       e, nb, denom, (float*)d_out);
}

// Round 2
// 392.568 us; speedup vs baseline: 1.2027x; 1.2027x over previous
//
#include <hip/hip_runtime.h>
#include <hip/hip_bf16.h>
#include <stdint.h>

#define N_NODES_C 1000000
#define N_GRAPHS_C 4096

typedef __attribute__((ext_vector_type(8))) __bf16 bf16x8;
typedef __attribute__((ext_vector_type(4))) float f32x4;

__device__ __forceinline__ unsigned short f2bf(float f) {
    union { float f; unsigned int u; } v; v.f = f;
    unsigned int r = v.u + 0x7FFFu + ((v.u >> 16) & 1u);   // RNE
    return (unsigned short)(r >> 16);
}
__device__ __forceinline__ unsigned int pack2(float a, float b) {
    return (unsigned int)f2bf(a) | ((unsigned int)f2bf(b) << 16);
}

// Stage 0: per-graph bias c[b][j] = bn[j] + (global_attr[b]@Wg + bg) @ Wn_bot[:,j]
// 4 graphs per 256-thread block; Wn_bot staged once per block in LDS.
// Block 0 additionally emits BT (Wn_top^T in bf16); every block zeroes its 4 denoms.
__global__ __launch_bounds__(256) void stage0_kernel(
    const float* __restrict__ ga, const float* __restrict__ Wg,
    const float* __restrict__ bg, const float* __restrict__ Wn,
    const float* __restrict__ bn,
    float* __restrict__ c, unsigned short* __restrict__ BT,
    float* __restrict__ denom)
{
    __shared__ float Wns[64 * 64];   // Wn rows 64..127 (16 KB)
    __shared__ float gs[4][64];
    int t = threadIdx.x;
#pragma unroll
    for (int i = 0; i < 4; ++i)
        ((float4*)Wns)[t + i * 256] = ((const float4*)(Wn + 64 * 64))[t + i * 256];
    if (blockIdx.x == 0) {
#pragma unroll
        for (int i = 0; i < 16; ++i) {
            int flat = t * 16 + i;           // BT[n][k] = Wn[k][n]
            int n = flat >> 6, k = flat & 63;
            BT[flat] = f2bf(Wn[k * 64 + n]);
        }
    }
    int gl = t >> 6, j = t & 63;
    int b = blockIdx.x * 4 + gl;
    float acc = bg[j];
#pragma unroll
    for (int m = 0; m < 3; ++m) acc += ga[b * 3 + m] * Wg[m * 64 + j];
    gs[gl][j] = acc;
    __syncthreads();
    float cj = bn[j];
#pragma unroll 16
    for (int k = 0; k < 64; ++k) cj += gs[gl][k] * Wns[k * 64 + j];
    c[b * 64 + j] = cj;
    if (j == 0) denom[b] = 0.0f;
}

// Main: all-register pipeline. Per wave: 64 nodes (4 tiles of 16).
// A fragments loaded straight from global x (each element touched exactly once
// device-wide), converted to bf16 in registers; B fragments from L2-resident BT.
// No LDS, no barriers.
__global__ __launch_bounds__(256, 4) void node_kernel(
    const float* __restrict__ x, const int* __restrict__ nb,
    const float* __restrict__ c, const unsigned short* __restrict__ BT,
    const float* __restrict__ Wa, const float* __restrict__ ba,
    float* __restrict__ e, float* __restrict__ denom)
{
    int t = threadIdx.x;
    int wave = t >> 6, lane = t & 63;
    int quad = lane >> 4, l15 = lane & 15;
    long base = (long)blockIdx.x * 256 + wave * 64;   // first node of this wave
    bool is64 = nb[N_NODES_C - 1] < 1024;   // int64 -> high word (0); int32 -> 4095

    // B fragments: B[k][n], lane holds n = l15 (+16*nt), k = quad*8 + j (+32*kh)
    bf16x8 bfrag[4][2];
#pragma unroll
    for (int nt = 0; nt < 4; ++nt)
#pragma unroll
        for (int kh = 0; kh < 2; ++kh)
            bfrag[nt][kh] = *(const bf16x8*)&BT[(nt * 16 + l15) * 64 + quad * 8 + kh * 32];

    float wa[4];
    float bav = ba[0];
#pragma unroll
    for (int nt = 0; nt < 4; ++nt) wa[nt] = Wa[nt * 16 + l15];

#pragma unroll
    for (int t4 = 0; t4 < 4; ++t4) {
        long arow = base + t4 * 16 + l15;
        float4 v0 = make_float4(0.f, 0.f, 0.f, 0.f), v1 = v0, v2 = v0, v3 = v0;
        if (arow < N_NODES_C) {
            const float4* xp = (const float4*)(x + arow * 64);
            v0 = xp[quad * 2];
            v1 = xp[quad * 2 + 1];
            v2 = xp[8 + quad * 2];
            v3 = xp[8 + quad * 2 + 1];
        }
        union { bf16x8 v; unsigned int u[4]; } A0, A1;
        A0.u[0] = pack2(v0.x, v0.y); A0.u[1] = pack2(v0.z, v0.w);
        A0.u[2] = pack2(v1.x, v1.y); A0.u[3] = pack2(v1.z, v1.w);
        A1.u[0] = pack2(v2.x, v2.y); A1.u[1] = pack2(v2.z, v2.w);
        A1.u[2] = pack2(v3.x, v3.y); A1.u[3] = pack2(v3.z, v3.w);

        f32x4 acc[4];
#pragma unroll
        for (int nt = 0; nt < 4; ++nt) {
            acc[nt] = (f32x4){0.f, 0.f, 0.f, 0.f};
            acc[nt] = __builtin_amdgcn_mfma_f32_16x16x32_bf16(A0.v, bfrag[nt][0], acc[nt], 0, 0, 0);
            acc[nt] = __builtin_amdgcn_mfma_f32_16x16x32_bf16(A1.v, bfrag[nt][1], acc[nt], 0, 0, 0);
        }

        // Epilogue. C/D layout: col = l15 + 16*nt, rows = tilebase + quad*4 + reg
        long r0 = base + t4 * 16 + quad * 4;    // global node idx of reg 0
        int sg0 = 0, sg1 = 0, sg2 = 0, sg3 = 0;
        if (is64) {
            if (r0 + 0 < N_NODES_C) sg0 = nb[2 * (r0 + 0)];
            if (r0 + 1 < N_NODES_C) sg1 = nb[2 * (r0 + 1)];
            if (r0 + 2 < N_NODES_C) sg2 = nb[2 * (r0 + 2)];
            if (r0 + 3 < N_NODES_C) sg3 = nb[2 * (r0 + 3)];
        } else {
            if (r0 + 0 < N_NODES_C) sg0 = nb[r0 + 0];
            if (r0 + 1 < N_NODES_C) sg1 = nb[r0 + 1];
            if (r0 + 2 < N_NODES_C) sg2 = nb[r0 + 2];
            if (r0 + 3 < N_NODES_C) sg3 = nb[r0 + 3];
        }
        bool uni = (sg0 == sg3);               // sorted -> ends equal => all equal
        float sp0 = 0.f, sp1 = 0.f, sp2 = 0.f, sp3 = 0.f;
#pragma unroll
        for (int nt = 0; nt < 4; ++nt) {
            int col = nt * 16 + l15;
            float c0, c1, c2, c3;
            if (uni) { c0 = c[sg0 * 64 + col]; c1 = c0; c2 = c0; c3 = c0; }
            else {
                c0 = c[sg0 * 64 + col]; c1 = c[sg1 * 64 + col];
                c2 = c[sg2 * 64 + col]; c3 = c[sg3 * 64 + col];
            }
            float y0 = acc[nt].x + c0, y1 = acc[nt].y + c1;
            float y2 = acc[nt].z + c2, y3 = acc[nt].w + c3;
            sp0 += __logf(1.f + __expf(y0)) * wa[nt];
            sp1 += __logf(1.f + __expf(y1)) * wa[nt];
            sp2 += __logf(1.f + __expf(y2)) * wa[nt];
            sp3 += __logf(1.f + __expf(y3)) * wa[nt];
        }
#pragma unroll
        for (int off = 1; off < 16; off <<= 1) {   // xor 1,2,4,8 stays in the quad
            sp0 += __shfl_xor(sp0, off, 64);
            sp1 += __shfl_xor(sp1, off, 64);
            sp2 += __shfl_xor(sp2, off, 64);
            sp3 += __shfl_xor(sp3, off, 64);
        }
        float e0 = __expf(sp0 + bav), e1 = __expf(sp1 + bav);
        float e2 = __expf(sp2 + bav), e3 = __expf(sp3 + bav);
        if (l15 == 0) {
            if (r0 + 3 < N_NODES_C) {
                *(float4*)&e[r0] = make_float4(e0, e1, e2, e3);
                float s = e0; int cur = sg0;
                if (sg1 == cur) s += e1; else { atomicAdd(&denom[cur], s); cur = sg1; s = e1; }
                if (sg2 == cur) s += e2; else { atomicAdd(&denom[cur], s); cur = sg2; s = e2; }
                if (sg3 == cur) s += e3; else { atomicAdd(&denom[cur], s); cur = sg3; s = e3; }
                atomicAdd(&denom[cur], s);
            } else {
                float ev[4] = {e0, e1, e2, e3};
                int sg[4] = {sg0, sg1, sg2, sg3};
                for (int i = 0; i < 4; ++i) {
                    if (r0 + i < N_NODES_C) {
                        e[r0 + i] = ev[i];
                        atomicAdd(&denom[sg[i]], ev[i]);
                    }
                }
            }
        }
    }
}

// Finalize: w = e / denom[seg]
__global__ __launch_bounds__(256) void fin_kernel(
    const float* __restrict__ e, const int* __restrict__ nb,
    const float* __restrict__ denom, float* __restrict__ out)
{
    long node0 = (long)(blockIdx.x * 256 + threadIdx.x) * 4;
    if (node0 >= N_NODES_C) return;
    bool is64 = nb[N_NODES_C - 1] < 1024;
    float4 ev = *(const float4*)&e[node0];
    int s0, s1, s2, s3;
    if (is64) {
        int4 a = *(const int4*)&nb[2 * node0];
        int4 b = *(const int4*)&nb[2 * node0 + 4];
        s0 = a.x; s1 = a.z; s2 = b.x; s3 = b.z;
    } else {
        int4 a = *(const int4*)&nb[node0];
        s0 = a.x; s1 = a.y; s2 = a.z; s3 = a.w;
    }
    float4 w;
    w.x = ev.x / denom[s0];
    w.y = ev.y / denom[s1];
    w.z = ev.z / denom[s2];
    w.w = ev.w / denom[s3];
    *(float4*)&out[node0] = w;
}

extern "C" void kernel_launch(void* const* d_in, const int* in_sizes, int n_in,
                              void* d_out, int out_size, void* d_ws, size_t ws_size,
                              hipStream_t stream) {
    const float* x  = (const float*)d_in[0];
    const int*   nb = (const int*)d_in[1];
    const float* ga = (const float*)d_in[2];
    const float* Wg = (const float*)d_in[3];
    const float* bg = (const float*)d_in[4];
    const float* Wn = (const float*)d_in[5];
    const float* bn = (const float*)d_in[6];
    const float* Wa = (const float*)d_in[7];
    const float* ba = (const float*)d_in[8];

    char* ws = (char*)d_ws;
    float* e            = (float*)(ws);                              // 4,000,000 B
    float* c            = (float*)(ws + 4194304);                    // 1 MB
    unsigned short* BT  = (unsigned short*)(ws + 4194304 + 1048576); // 8 KB
    float* denom        = (float*)(ws + 4194304 + 1048576 + 8192);   // 16 KB

    hipLaunchKernelGGL(stage0_kernel, dim3(N_GRAPHS_C / 4), dim3(256), 0, stream,
                       ga, Wg, bg, Wn, bn, c, BT, denom);
    hipLaunchKernelGGL(node_kernel, dim3((N_NODES_C + 255) / 256), dim3(256), 0, stream,
                       x, nb, c, BT, Wa, ba, e, denom);
    hipLaunchKernelGGL(fin_kernel, dim3((N_NODES_C / 4 + 255) / 256), dim3(256), 0, stream,
                       e, nb, denom, (float*)d_out);
}